// Round 2
// baseline (512.513 us; speedup 1.0000x reference)
//
#include <hip/hip_runtime.h>
#include <math.h>

// RegionalGNN: B=8192, NC=8, H=256, HD=1024, L=3.
// Algebraic collapse: Wqk = Wq@Wk^T (fold 1/16), Wvo = Wv@Wo; attention works on
// H=256-wide tensors only. All heavy GEMMs are bf16 MFMA 16x16x32, f32 accum.
// R2 fix: k_convert block offsets were 3x too large for Wq/Wk/Wv (OOB read -> abort).
//         Workspace aliased down to ~65 MB (weights staged inside X/T regions).

typedef short bf16x8 __attribute__((ext_vector_type(8)));
typedef float f32x4  __attribute__((ext_vector_type(4)));

__device__ __forceinline__ float bflo(unsigned int u){ return __uint_as_float(u << 16); }
__device__ __forceinline__ float bfhi(unsigned int u){ return __uint_as_float(u & 0xffff0000u); }
__device__ __forceinline__ unsigned short f2bf(float f){
  unsigned int u = __float_as_uint(f);
  u += 0x7fffu + ((u >> 16) & 1u);          // RNE
  return (unsigned short)(u >> 16);
}
__device__ __forceinline__ void unpack8(uint4 a, float* o){
  o[0]=bflo(a.x); o[1]=bfhi(a.x); o[2]=bflo(a.y); o[3]=bfhi(a.y);
  o[4]=bflo(a.z); o[5]=bfhi(a.z); o[6]=bflo(a.w); o[7]=bfhi(a.w);
}
__device__ __forceinline__ uint4 pack8(const float* v){
  uint4 r;
  r.x = (unsigned int)f2bf(v[0]) | ((unsigned int)f2bf(v[1]) << 16);
  r.y = (unsigned int)f2bf(v[2]) | ((unsigned int)f2bf(v[3]) << 16);
  r.z = (unsigned int)f2bf(v[4]) | ((unsigned int)f2bf(v[5]) << 16);
  r.w = (unsigned int)f2bf(v[6]) | ((unsigned int)f2bf(v[7]) << 16);
  return r;
}
__device__ __forceinline__ float dot8(uint4 a, uint4 b, float s){
  s = fmaf(bflo(a.x), bflo(b.x), s); s = fmaf(bfhi(a.x), bfhi(b.x), s);
  s = fmaf(bflo(a.y), bflo(b.y), s); s = fmaf(bfhi(a.y), bfhi(b.y), s);
  s = fmaf(bflo(a.z), bflo(b.z), s); s = fmaf(bfhi(a.z), bfhi(b.z), s);
  s = fmaf(bflo(a.w), bflo(b.w), s); s = fmaf(bfhi(a.w), bfhi(b.w), s);
  return s;
}
__device__ __forceinline__ void gload16(const void* g, void* l){
  __builtin_amdgcn_global_load_lds(
      (const __attribute__((address_space(1))) unsigned int*)g,
      (__attribute__((address_space(3))) unsigned int*)l, 16, 0, 0);
}

// ---------------- convert f32 -> bf16 (rf, Wq, Wk, Wv) ----------------
struct CvP { const float* src[4]; short* dst[4]; int boff[5]; };
__global__ __launch_bounds__(256) void k_convert(CvP p){
  int bid = blockIdx.x, s = 0;
  while (bid >= p.boff[s+1]) s++;
  size_t e = (size_t)(bid - p.boff[s]) * 2048 + (size_t)threadIdx.x * 8;
  const float* src = p.src[s] + e;
  float4 v0 = *(const float4*)src;
  float4 v1 = *(const float4*)(src + 4);
  float v[8] = {v0.x,v0.y,v0.z,v0.w,v1.x,v1.y,v1.z,v1.w};
  *(uint4*)(p.dst[s] + e) = pack8(v);
}

// ---------------- transpose + convert (Wi, Wo x3, Wp) ----------------
struct TrP { const float* src[5]; short* dst[5]; int rows[5]; int cols[5]; int toff[6]; };
__global__ __launch_bounds__(256) void k_transpose(TrP p){
  __shared__ float tile[64][65];
  int bid = blockIdx.x, s = 0;
  while (bid >= p.toff[s+1]) s++;
  int ti = bid - p.toff[s];
  int cols = p.cols[s], rows = p.rows[s];
  int ntc = cols >> 6;
  int r0 = (ti / ntc) * 64, c0 = (ti % ntc) * 64;
  const float* src = p.src[s];
  int row = threadIdx.x >> 2, jb = (threadIdx.x & 3) * 16;
  #pragma unroll
  for (int j = 0; j < 16; j += 4){
    float4 v = *(const float4*)(src + (size_t)(r0 + row) * cols + c0 + jb + j);
    tile[row][jb+j] = v.x; tile[row][jb+j+1] = v.y; tile[row][jb+j+2] = v.z; tile[row][jb+j+3] = v.w;
  }
  __syncthreads();
  short* dst = p.dst[s];
  float tmp[16];
  #pragma unroll
  for (int j = 0; j < 16; j++) tmp[j] = tile[jb + j][row];
  #pragma unroll
  for (int j = 0; j < 16; j += 8)
    *(uint4*)(dst + (size_t)(c0 + row) * rows + r0 + jb + j) = pack8(&tmp[j]);
}

// ---------------- bias-fold vectors: cq, ck, cvo, c0 per layer ----------------
__global__ __launch_bounds__(256) void k_vecs(const float* Wq, const float* bq,
    const float* Wk, const float* bk, const float* Wv, const float* bv,
    const float* Wo, const float* bo, float* cq, float* ck, float* cvo, float* c0){
  int l = blockIdx.x, t = threadIdx.x;
  __shared__ float sbq[1024], sbk[1024], sbv[1024];
  __shared__ float red[256];
  for (int i = t; i < 1024; i += 256){
    sbq[i] = bq[l*1024 + i]; sbk[i] = bk[l*1024 + i]; sbv[i] = bv[l*1024 + i];
  }
  __syncthreads();
  const float* wq = Wq + (size_t)l*262144 + (size_t)t*1024;
  const float* wk = Wk + (size_t)l*262144 + (size_t)t*1024;
  float aq = 0.f, ak = 0.f;
  for (int d = 0; d < 1024; d++){ aq = fmaf(wq[d], sbk[d], aq); ak = fmaf(wk[d], sbq[d], ak); }
  cq[l*256 + t] = aq * 0.0625f;
  ck[l*256 + t] = ak * 0.0625f;
  const float* wo = Wo + (size_t)l*262144;
  float av = 0.f;
  for (int d = 0; d < 1024; d++) av = fmaf(sbv[d], wo[(size_t)d*256 + t], av);
  cvo[l*256 + t] = av + bo[l*256 + t];
  float pp = 0.f;
  for (int d = t; d < 1024; d += 256) pp = fmaf(sbq[d], sbk[d], pp);
  red[t] = pp; __syncthreads();
  for (int o = 128; o > 0; o >>= 1){ if (t < o) red[t] += red[t + o]; __syncthreads(); }
  if (t == 0) c0[l] = red[0] * 0.0625f;
}

// ---------------- 128x128 MFMA GEMM (A[M,K] bf16, Bt[N,K] bf16) ----------------
// MODE 0: C[r*ldc+n] = bf16(acc*scale).  MODE 1: input-proj epilogue -> X broadcast+emb.
struct GDesc { const short* A; const short* Bt; short* C; int K; float scale; };
struct GemmP { GDesc d[6]; const float* bi; const float* emb; short* X; };
template<int MODE>
__global__ __launch_bounds__(256) void k_gemm128(GemmP p){
  GDesc g = p.d[blockIdx.z];
  const int tid = threadIdx.x, lane = tid & 63, w = tid >> 6;
  const int wm = w >> 1, wn = w & 1;
  __shared__ alignas(16) short As[128*32];
  __shared__ alignas(16) short Bs[128*32];
  __shared__ float s_bi[256];
  __shared__ float s_emb[2048];
  if constexpr (MODE == 1){
    s_bi[tid] = p.bi[tid];
    for (int i = tid; i < 2048; i += 256) s_emb[i] = p.emb[i];
  }
  const int K = g.K;
  const short* Ab = g.A + (size_t)blockIdx.x * 128 * K;
  const short* Bb = g.Bt + (size_t)blockIdx.y * 128 * K;
  f32x4 acc[4][4] = {};
  for (int k0 = 0; k0 < K; k0 += 32){
    #pragma unroll
    for (int i = 0; i < 2; i++){
      int ch = w*2 + i;
      int ro = ch*16 + (lane >> 2);
      int co = k0 + (lane & 3) * 8;
      gload16(Ab + (size_t)ro * K + co, &As[ch*512]);
      gload16(Bb + (size_t)ro * K + co, &Bs[ch*512]);
    }
    __syncthreads();
    bf16x8 av[4], bv[4];
    #pragma unroll
    for (int mi = 0; mi < 4; mi++)
      av[mi] = *(const bf16x8*)&As[(wm*64 + mi*16 + (lane & 15)) * 32 + (lane >> 4) * 8];
    #pragma unroll
    for (int nj = 0; nj < 4; nj++)
      bv[nj] = *(const bf16x8*)&Bs[(wn*64 + nj*16 + (lane & 15)) * 32 + (lane >> 4) * 8];
    #pragma unroll
    for (int mi = 0; mi < 4; mi++)
      #pragma unroll
      for (int nj = 0; nj < 4; nj++)
        acc[mi][nj] = __builtin_amdgcn_mfma_f32_16x16x32_bf16(av[mi], bv[nj], acc[mi][nj], 0, 0, 0);
    __syncthreads();
  }
  if constexpr (MODE == 0){
    const int ldc = gridDim.y * 128;
    #pragma unroll
    for (int mi = 0; mi < 4; mi++)
      #pragma unroll
      for (int nj = 0; nj < 4; nj++){
        int rm0 = blockIdx.x*128 + wm*64 + mi*16 + (lane >> 4) * 4;
        int cn  = blockIdx.y*128 + wn*64 + nj*16 + (lane & 15);
        #pragma unroll
        for (int j = 0; j < 4; j++)
          g.C[(size_t)(rm0 + j) * ldc + cn] = (short)f2bf(acc[mi][nj][j] * g.scale);
      }
  } else {
    #pragma unroll
    for (int mi = 0; mi < 4; mi++)
      #pragma unroll
      for (int nj = 0; nj < 4; nj++){
        int rm0 = blockIdx.x*128 + wm*64 + mi*16 + (lane >> 4) * 4;
        int cn  = blockIdx.y*128 + wn*64 + nj*16 + (lane & 15);
        #pragma unroll
        for (int j = 0; j < 4; j++){
          float base = acc[mi][nj][j] + s_bi[cn];
          #pragma unroll
          for (int c = 0; c < 8; c++)
            p.X[((size_t)(rm0 + j) * 8 + c) * 256 + cn] = (short)f2bf(base + s_emb[c*256 + cn]);
        }
      }
  }
}

// ---------------- attention: scores/softmax/attn@x, one wave per batch ----------------
__global__ __launch_bounds__(256) void k_attn(const short* X, short* T,
    const float* cq, const float* ck, const float* c0p){
  const int tid = threadIdx.x, lane = tid & 63, w = tid >> 6;
  const int b = blockIdx.x * 4 + w;
  __shared__ alignas(16) short Ts[4][8][264];
  __shared__ alignas(16) short Xs[4][8][264];
  __shared__ float cqs[256], cks[256];
  cqs[tid] = cq[tid]; cks[tid] = ck[tid];
  const size_t base = (size_t)b * 2048;
  #pragma unroll
  for (int it = 0; it < 4; it++){
    int gi = it*512 + lane*8;
    int r = gi >> 8, c = gi & 255;
    *(uint4*)&Ts[w][r][c] = *(const uint4*)(T + base + gi);
    *(uint4*)&Xs[w][r][c] = *(const uint4*)(X + base + gi);
  }
  __syncthreads();
  const int n = lane >> 3, m = lane & 7;
  float s = 0.f;
  #pragma unroll 4
  for (int d0 = 0; d0 < 256; d0 += 8){
    uint4 ta = *(const uint4*)&Ts[w][n][d0];
    uint4 xa = *(const uint4*)&Xs[w][m][d0];
    s = dot8(ta, xa, s);
  }
  // sq_n = x_n . cq ; sk_n = x_n . ck  (octet n reduces over its row)
  float pq = 0.f, pk = 0.f;
  #pragma unroll
  for (int i = 0; i < 32; i += 8){
    uint4 xv = *(const uint4*)&Xs[w][n][m*32 + i];
    float xf[8]; unpack8(xv, xf);
    #pragma unroll
    for (int j = 0; j < 8; j++){
      pq = fmaf(xf[j], cqs[m*32 + i + j], pq);
      pk = fmaf(xf[j], cks[m*32 + i + j], pk);
    }
  }
  #pragma unroll
  for (int o = 1; o < 8; o <<= 1){ pq += __shfl_xor(pq, o); pk += __shfl_xor(pk, o); }
  float skm = __shfl(pk, m << 3);     // sk of row m (from octet m)
  s = s + pq + skm + c0p[0];
  const unsigned long long MASK64 = 0x02191D69752B857EULL;  // ADJ rows as bytes
  bool ok = (MASK64 >> (lane)) & 1ull;  // bit n*8+m == lane
  float sv = ok ? s : -3.0e38f;
  float mx = sv;
  #pragma unroll
  for (int o = 1; o < 8; o <<= 1) mx = fmaxf(mx, __shfl_xor(mx, o));
  float e = ok ? __expf(sv - mx) : 0.f;
  float sum = e;
  #pragma unroll
  for (int o = 1; o < 8; o <<= 1) sum += __shfl_xor(sum, o);
  float at = e / sum;
  float am[8];
  #pragma unroll
  for (int mm = 0; mm < 8; mm++) am[mm] = __shfl(at, (n << 3) + mm);
  // y[n] = sum_m attn[n][m] * x[m]; lane (n,m) handles d = m*8 + cb*64, in-place over T
  #pragma unroll
  for (int cb = 0; cb < 4; cb++){
    int d0 = m*8 + cb*64;
    float a8[8] = {0,0,0,0,0,0,0,0};
    #pragma unroll
    for (int mm = 0; mm < 8; mm++){
      uint4 xv = *(const uint4*)&Xs[w][mm][d0];
      float xf[8]; unpack8(xv, xf);
      #pragma unroll
      for (int j = 0; j < 8; j++) a8[j] = fmaf(am[mm], xf[j], a8[j]);
    }
    *(uint4*)(T + base + n*256 + d0) = pack8(a8);
  }
}

// ---------------- BM=64 x BN=256 GEMM with fused epilogue ----------------
// MODE 2: out = Y@Wvo + cvo; X = LN(X + out)   (writes X bf16)
// MODE 3: A = GDP-reduce(X); p = LN(A@Wp + bp); out = gelu_erf(p)  (writes f32)
template<int MODE>
__global__ __launch_bounds__(256) void k_gemmW(const short* Ax, const short* Bt,
    const float* addv, const float* gv, const float* bv2, short* Xio, float* outp){
  const int K = 256;
  const int tid = threadIdx.x, lane = tid & 63, w = tid >> 6;
  __shared__ alignas(16) short As[64*32];
  __shared__ alignas(16) short Bs[256*32];
  __shared__ alignas(16) unsigned short Ob[64*256];
  __shared__ float s_add[256], s_g[256], s_b[256];
  s_add[tid] = addv[tid]; s_g[tid] = gv[tid]; s_b[tid] = bv2[tid];
  const int r0 = blockIdx.x * 64;
  f32x4 acc[4][4] = {};
  for (int k0 = 0; k0 < K; k0 += 32){
    if constexpr (MODE == 2){
      const short* ga = Ax + (size_t)(r0 + w*16 + (lane >> 2)) * K + k0 + (lane & 3) * 8;
      gload16(ga, &As[w*512]);
    } else {
      const float GDPc[8] = {0.4f,0.15f,0.12f,0.1f,0.08f,0.08f,0.05f,0.02f};
      int row = tid >> 2, kk = (tid & 3) * 8;
      const short* xr = Ax + ((size_t)(r0 + row) * 8) * 256 + k0 + kk;
      float v8[8] = {0,0,0,0,0,0,0,0};
      #pragma unroll
      for (int c = 0; c < 8; c++){
        uint4 xv = *(const uint4*)(xr + (size_t)c * 256);
        float xf[8]; unpack8(xv, xf);
        #pragma unroll
        for (int j = 0; j < 8; j++) v8[j] = fmaf(GDPc[c], xf[j], v8[j]);
      }
      *(uint4*)&As[row*32 + kk] = pack8(v8);
    }
    #pragma unroll
    for (int i = 0; i < 4; i++){
      int ch = w*4 + i;
      const short* gb = Bt + (size_t)(ch*16 + (lane >> 2)) * K + k0 + (lane & 3) * 8;
      gload16(gb, &Bs[ch*512]);
    }
    __syncthreads();
    bf16x8 av[4], bvv[4];
    #pragma unroll
    for (int mi = 0; mi < 4; mi++)
      av[mi] = *(const bf16x8*)&As[(mi*16 + (lane & 15)) * 32 + (lane >> 4) * 8];
    #pragma unroll
    for (int nj = 0; nj < 4; nj++)
      bvv[nj] = *(const bf16x8*)&Bs[(w*64 + nj*16 + (lane & 15)) * 32 + (lane >> 4) * 8];
    #pragma unroll
    for (int mi = 0; mi < 4; mi++)
      #pragma unroll
      for (int nj = 0; nj < 4; nj++)
        acc[mi][nj] = __builtin_amdgcn_mfma_f32_16x16x32_bf16(av[mi], bvv[nj], acc[mi][nj], 0, 0, 0);
    __syncthreads();
  }
  #pragma unroll
  for (int mi = 0; mi < 4; mi++)
    #pragma unroll
    for (int nj = 0; nj < 4; nj++){
      int rr0 = mi*16 + (lane >> 4) * 4;
      int cc  = w*64 + nj*16 + (lane & 15);
      #pragma unroll
      for (int j = 0; j < 4; j++)
        Ob[(rr0 + j) * 256 + cc] = f2bf(acc[mi][nj][j] + s_add[cc]);
    }
  __syncthreads();
  // LayerNorm: 4 lanes per row (64 cols each)
  int row = tid >> 2, part = tid & 3;
  int cb0 = part * 64;
  const short* xg = Xio + (size_t)(r0 + row) * 256;   // only deref'd in MODE 2
  float sm = 0.f, s2 = 0.f;
  for (int i = 0; i < 64; i += 8){
    uint4 ov = *(const uint4*)&Ob[row*256 + cb0 + i];
    float of[8]; unpack8(ov, of);
    if constexpr (MODE == 2){
      uint4 xv = *(const uint4*)(xg + cb0 + i);
      float xf[8]; unpack8(xv, xf);
      #pragma unroll
      for (int j = 0; j < 8; j++){ float t = of[j] + xf[j]; sm += t; s2 = fmaf(t, t, s2); }
    } else {
      #pragma unroll
      for (int j = 0; j < 8; j++){ float t = of[j]; sm += t; s2 = fmaf(t, t, s2); }
    }
  }
  sm += __shfl_xor(sm, 1); sm += __shfl_xor(sm, 2);
  s2 += __shfl_xor(s2, 1); s2 += __shfl_xor(s2, 2);
  float mean = sm * (1.f/256.f);
  float var  = s2 * (1.f/256.f) - mean * mean;
  float rstd = rsqrtf(fmaxf(var, 0.f) + 1e-5f);
  for (int i = 0; i < 64; i += 8){
    int c = cb0 + i;
    uint4 ov = *(const uint4*)&Ob[row*256 + c];
    float of[8]; unpack8(ov, of);
    float y8[8];
    if constexpr (MODE == 2){
      uint4 xv = *(const uint4*)(xg + c);
      float xf[8]; unpack8(xv, xf);
      #pragma unroll
      for (int j = 0; j < 8; j++){
        float t = of[j] + xf[j];
        y8[j] = (t - mean) * rstd * s_g[c + j] + s_b[c + j];
      }
      *(uint4*)(Xio + (size_t)(r0 + row) * 256 + c) = pack8(y8);
    } else {
      #pragma unroll
      for (int j = 0; j < 8; j++){
        float t = of[j];
        float y = (t - mean) * rstd * s_g[c + j] + s_b[c + j];
        y8[j] = 0.5f * y * (1.0f + erff(y * 0.70710678118654752f));
      }
      float* op = outp + (size_t)(r0 + row) * 256 + c;
      float4 st0 = {y8[0], y8[1], y8[2], y8[3]};
      float4 st1 = {y8[4], y8[5], y8[6], y8[7]};
      *(float4*)op = st0; *(float4*)(op + 4) = st1;
    }
  }
}

extern "C" void kernel_launch(void* const* d_in, const int* in_sizes, int n_in,
                              void* d_out, int out_size, void* d_ws, size_t ws_size,
                              hipStream_t stream){
  (void)in_sizes; (void)n_in; (void)out_size; (void)ws_size;
  const float* rf  = (const float*)d_in[0];
  const float* Wi  = (const float*)d_in[1];
  const float* bi  = (const float*)d_in[2];
  const float* emb = (const float*)d_in[3];
  const float* Wq  = (const float*)d_in[4];
  const float* bq  = (const float*)d_in[5];
  const float* Wk  = (const float*)d_in[6];
  const float* bk  = (const float*)d_in[7];
  const float* Wv  = (const float*)d_in[8];
  const float* bv  = (const float*)d_in[9];
  const float* Wo  = (const float*)d_in[10];
  const float* bo  = (const float*)d_in[11];
  const float* lng = (const float*)d_in[12];
  const float* lnb = (const float*)d_in[13];
  const float* Wp  = (const float*)d_in[14];
  const float* bp  = (const float*)d_in[15];
  const float* lpg = (const float*)d_in[16];
  const float* lpb = (const float*)d_in[17];

  // Workspace layout (peak ~65.1 MB):
  //   X [65536][256] bf16 @ 0        (transient weight copies staged here pre-X)
  //   T [65536][256] bf16 @ 32MB     (rfb staged here pre-T)
  //   small persistent tail @ 64MB
  char* ws = (char*)d_ws;
  short* X    = (short*)(ws);
  short* T    = (short*)(ws + 33554432ull);
  // transient: consumed by precompute GEMMs / input-proj GEMM before X/T written
  short* Wqb  = (short*)(ws);                      // [3][256][1024] bf16 (in X region)
  short* Wkb  = (short*)(ws + 1572864ull);
  short* Wvb  = (short*)(ws + 3145728ull);
  short* WoTb = (short*)(ws + 4718592ull);         // [3][256][1024] (Wo^T per layer)
  short* rfb  = (short*)(ws + 33554432ull);        // [8192][512] bf16 (in T region)
  // persistent tail
  short* WiTb = (short*)(ws + 67108864ull);        // [256][512]
  short* WpTb = (short*)(ws + 67371008ull);        // [256][256]
  short* Wqk  = (short*)(ws + 67502080ull);        // [3][256][256] Bt for GEMM1 (scaled 1/16)
  short* Wvo  = (short*)(ws + 67895296ull);        // [3][256][256] Bt for GEMM2
  float* cqv  = (float*)(ws + 68288512ull);
  float* ckv  = (float*)(ws + 68291584ull);
  float* cvov = (float*)(ws + 68294656ull);
  float* c0v  = (float*)(ws + 68297728ull);

  { CvP cv;
    cv.src[0]=rf; cv.dst[0]=rfb;
    cv.src[1]=Wq; cv.dst[1]=Wqb;
    cv.src[2]=Wk; cv.dst[2]=Wkb;
    cv.src[3]=Wv; cv.dst[3]=Wvb;
    // rf: 8192*512/2048 = 2048 blocks; Wq/Wk/Wv: 3*256*1024/2048 = 384 blocks each
    cv.boff[0]=0; cv.boff[1]=2048; cv.boff[2]=2432; cv.boff[3]=2816; cv.boff[4]=3200;
    k_convert<<<dim3(3200), dim3(256), 0, stream>>>(cv); }

  { TrP tp;
    tp.src[0]=Wi;          tp.dst[0]=WiTb;          tp.rows[0]=512;  tp.cols[0]=256;
    tp.src[1]=Wo;          tp.dst[1]=WoTb;          tp.rows[1]=1024; tp.cols[1]=256;
    tp.src[2]=Wo+262144;   tp.dst[2]=WoTb+262144;   tp.rows[2]=1024; tp.cols[2]=256;
    tp.src[3]=Wo+524288;   tp.dst[3]=WoTb+524288;   tp.rows[3]=1024; tp.cols[3]=256;
    tp.src[4]=Wp;          tp.dst[4]=WpTb;          tp.rows[4]=256;  tp.cols[4]=256;
    tp.toff[0]=0; tp.toff[1]=32; tp.toff[2]=96; tp.toff[3]=160; tp.toff[4]=224; tp.toff[5]=240;
    k_transpose<<<dim3(240), dim3(256), 0, stream>>>(tp); }

  k_vecs<<<dim3(3), dim3(256), 0, stream>>>(Wq, bq, Wk, bk, Wv, bv, Wo, bo, cqv, ckv, cvov, c0v);

  { GemmP g{};   // Wqk_bt[j][i] = (1/16) sum_d Wk[j,d]Wq[i,d] ; Wvo_bt[n][k] = sum_d Wo[d,n]Wv[k,d]
    for (int l = 0; l < 3; l++){
      g.d[l]   = GDesc{ Wkb  + l*262144, Wqb + l*262144, Wqk + l*65536, 1024, 0.0625f };
      g.d[3+l] = GDesc{ WoTb + l*262144, Wvb + l*262144, Wvo + l*65536, 1024, 1.0f };
    }
    k_gemm128<0><<<dim3(2,2,6), dim3(256), 0, stream>>>(g); }

  { GemmP g{};   // X[b,c,:] = rf@Wi + bi + emb[c]   (consumes rfb + weight copies, writes X)
    g.d[0] = GDesc{ rfb, WiTb, T, 512, 1.0f };
    g.bi = bi; g.emb = emb; g.X = X;
    k_gemm128<1><<<dim3(64,2,1), dim3(256), 0, stream>>>(g); }

  for (int l = 0; l < 3; l++){
    { GemmP g{};   // T = X @ Wqk (pre-scaled)
      g.d[0] = GDesc{ X, Wqk + l*65536, T, 256, 1.0f };
      k_gemm128<0><<<dim3(512,2,1), dim3(256), 0, stream>>>(g); }
    k_attn<<<dim3(2048), dim3(256), 0, stream>>>(X, T, cqv + l*256, ckv + l*256, c0v + l);
    k_gemmW<2><<<dim3(1024), dim3(256), 0, stream>>>(T, Wvo + l*65536, cvov + l*256,
                                                     lng + l*256, lnb + l*256, X, nullptr);
  }
  k_gemmW<3><<<dim3(128), dim3(256), 0, stream>>>(X, WpTb, bp, lpg, lpb, X, (float*)d_out);
}

// Round 3
// 460.846 us; speedup vs baseline: 1.1121x; 1.1121x over previous
//
#include <hip/hip_runtime.h>
#include <math.h>

// RegionalGNN: B=8192, NC=8, H=256, HD=1024, L=3.
// Algebraic collapse: Wqk = Wq@Wk^T (fold 1/16), Wvo = Wv@Wo; attention works on
// H=256-wide tensors only. All heavy GEMMs are bf16 MFMA 16x16x32, f32 accum.
// R3: k_vecs (96us @ 0.13% occupancy, serial uncoalesced dots) -> k_vecs2
//     (12 blocks, 8-lane row-dots on staged bf16 rows, ~5us).

typedef short bf16x8 __attribute__((ext_vector_type(8)));
typedef float f32x4  __attribute__((ext_vector_type(4)));

__device__ __forceinline__ float bflo(unsigned int u){ return __uint_as_float(u << 16); }
__device__ __forceinline__ float bfhi(unsigned int u){ return __uint_as_float(u & 0xffff0000u); }
__device__ __forceinline__ unsigned short f2bf(float f){
  unsigned int u = __float_as_uint(f);
  u += 0x7fffu + ((u >> 16) & 1u);          // RNE
  return (unsigned short)(u >> 16);
}
__device__ __forceinline__ void unpack8(uint4 a, float* o){
  o[0]=bflo(a.x); o[1]=bfhi(a.x); o[2]=bflo(a.y); o[3]=bfhi(a.y);
  o[4]=bflo(a.z); o[5]=bfhi(a.z); o[6]=bflo(a.w); o[7]=bfhi(a.w);
}
__device__ __forceinline__ uint4 pack8(const float* v){
  uint4 r;
  r.x = (unsigned int)f2bf(v[0]) | ((unsigned int)f2bf(v[1]) << 16);
  r.y = (unsigned int)f2bf(v[2]) | ((unsigned int)f2bf(v[3]) << 16);
  r.z = (unsigned int)f2bf(v[4]) | ((unsigned int)f2bf(v[5]) << 16);
  r.w = (unsigned int)f2bf(v[6]) | ((unsigned int)f2bf(v[7]) << 16);
  return r;
}
__device__ __forceinline__ float dot8(uint4 a, uint4 b, float s){
  s = fmaf(bflo(a.x), bflo(b.x), s); s = fmaf(bfhi(a.x), bfhi(b.x), s);
  s = fmaf(bflo(a.y), bflo(b.y), s); s = fmaf(bfhi(a.y), bfhi(b.y), s);
  s = fmaf(bflo(a.z), bflo(b.z), s); s = fmaf(bfhi(a.z), bfhi(b.z), s);
  s = fmaf(bflo(a.w), bflo(b.w), s); s = fmaf(bfhi(a.w), bfhi(b.w), s);
  return s;
}
__device__ __forceinline__ void gload16(const void* g, void* l){
  __builtin_amdgcn_global_load_lds(
      (const __attribute__((address_space(1))) unsigned int*)g,
      (__attribute__((address_space(3))) unsigned int*)l, 16, 0, 0);
}

// ---------------- convert f32 -> bf16 (rf, Wq, Wk, Wv) ----------------
struct CvP { const float* src[4]; short* dst[4]; int boff[5]; };
__global__ __launch_bounds__(256) void k_convert(CvP p){
  int bid = blockIdx.x, s = 0;
  while (bid >= p.boff[s+1]) s++;
  size_t e = (size_t)(bid - p.boff[s]) * 2048 + (size_t)threadIdx.x * 8;
  const float* src = p.src[s] + e;
  float4 v0 = *(const float4*)src;
  float4 v1 = *(const float4*)(src + 4);
  float v[8] = {v0.x,v0.y,v0.z,v0.w,v1.x,v1.y,v1.z,v1.w};
  *(uint4*)(p.dst[s] + e) = pack8(v);
}

// ---------------- transpose + convert (Wi, Wo x3, Wp) ----------------
struct TrP { const float* src[5]; short* dst[5]; int rows[5]; int cols[5]; int toff[6]; };
__global__ __launch_bounds__(256) void k_transpose(TrP p){
  __shared__ float tile[64][65];
  int bid = blockIdx.x, s = 0;
  while (bid >= p.toff[s+1]) s++;
  int ti = bid - p.toff[s];
  int cols = p.cols[s], rows = p.rows[s];
  int ntc = cols >> 6;
  int r0 = (ti / ntc) * 64, c0 = (ti % ntc) * 64;
  const float* src = p.src[s];
  int row = threadIdx.x >> 2, jb = (threadIdx.x & 3) * 16;
  #pragma unroll
  for (int j = 0; j < 16; j += 4){
    float4 v = *(const float4*)(src + (size_t)(r0 + row) * cols + c0 + jb + j);
    tile[row][jb+j] = v.x; tile[row][jb+j+1] = v.y; tile[row][jb+j+2] = v.z; tile[row][jb+j+3] = v.w;
  }
  __syncthreads();
  short* dst = p.dst[s];
  float tmp[16];
  #pragma unroll
  for (int j = 0; j < 16; j++) tmp[j] = tile[jb + j][row];
  #pragma unroll
  for (int j = 0; j < 16; j += 8)
    *(uint4*)(dst + (size_t)(c0 + row) * rows + r0 + jb + j) = pack8(&tmp[j]);
}

// ---------------- bias-fold vectors via bf16 row-dots ----------------
// job 0: cq[t] = (1/16) Wqb[l] row t . bk[l]
// job 1: ck[t] = (1/16) Wkb[l] row t . bq[l]
// job 2: cvo[t] =       WoTb[l] row t . bv[l] + bo[l,t]
// job 3: c0[l] = (1/16) bq[l] . bk[l]
__global__ __launch_bounds__(256) void k_vecs2(
    const short* Wqb, const short* Wkb, const short* WoTb,
    const float* bq, const float* bk, const float* bv, const float* bo,
    float* cq, float* ck, float* cvo, float* c0){
  const int job = blockIdx.x, l = blockIdx.y, tid = threadIdx.x;
  __shared__ float sv[1024];
  __shared__ float red[256];
  if (job == 3){
    float pp = 0.f;
    #pragma unroll
    for (int i = 0; i < 4; i++){
      int d = tid*4 + i;
      pp = fmaf(bq[l*1024 + d], bk[l*1024 + d], pp);
    }
    red[tid] = pp; __syncthreads();
    for (int o = 128; o > 0; o >>= 1){ if (tid < o) red[tid] += red[tid + o]; __syncthreads(); }
    if (tid == 0) c0[l] = red[0] * 0.0625f;
    return;
  }
  const short* rows = (job==0 ? Wqb : job==1 ? Wkb : WoTb) + (size_t)l*262144;
  const float* vecg = (job==0 ? bk : job==1 ? bq : bv) + l*1024;
  const float scale = (job == 2) ? 1.0f : 0.0625f;
  for (int i = tid; i < 1024; i += 256) sv[i] = vecg[i];
  __syncthreads();
  const int row = tid >> 3, sub = tid & 7;
  for (int pass = 0; pass < 8; pass++){
    int r = pass*32 + row;
    const short* rp = rows + (size_t)r*1024;
    float acc = 0.f;
    #pragma unroll
    for (int i = 0; i < 16; i++){
      int d = sub*8 + i*64;
      uint4 v = *(const uint4*)(rp + d);
      float f[8]; unpack8(v, f);
      #pragma unroll
      for (int j = 0; j < 8; j++) acc = fmaf(f[j], sv[d + j], acc);
    }
    acc += __shfl_xor(acc, 1); acc += __shfl_xor(acc, 2); acc += __shfl_xor(acc, 4);
    if (sub == 0){
      float o = acc * scale;
      if (job == 2) o += bo[l*256 + r];
      (job==0 ? cq : job==1 ? ck : cvo)[l*256 + r] = o;
    }
  }
}

// ---------------- 128x128 MFMA GEMM (A[M,K] bf16, Bt[N,K] bf16) ----------------
// MODE 0: C[r*ldc+n] = bf16(acc*scale).  MODE 1: input-proj epilogue -> X broadcast+emb.
struct GDesc { const short* A; const short* Bt; short* C; int K; float scale; };
struct GemmP { GDesc d[6]; const float* bi; const float* emb; short* X; };
template<int MODE>
__global__ __launch_bounds__(256) void k_gemm128(GemmP p){
  GDesc g = p.d[blockIdx.z];
  const int tid = threadIdx.x, lane = tid & 63, w = tid >> 6;
  const int wm = w >> 1, wn = w & 1;
  __shared__ alignas(16) short As[128*32];
  __shared__ alignas(16) short Bs[128*32];
  __shared__ float s_bi[256];
  __shared__ float s_emb[2048];
  if constexpr (MODE == 1){
    s_bi[tid] = p.bi[tid];
    for (int i = tid; i < 2048; i += 256) s_emb[i] = p.emb[i];
  }
  const int K = g.K;
  const short* Ab = g.A + (size_t)blockIdx.x * 128 * K;
  const short* Bb = g.Bt + (size_t)blockIdx.y * 128 * K;
  f32x4 acc[4][4] = {};
  for (int k0 = 0; k0 < K; k0 += 32){
    #pragma unroll
    for (int i = 0; i < 2; i++){
      int ch = w*2 + i;
      int ro = ch*16 + (lane >> 2);
      int co = k0 + (lane & 3) * 8;
      gload16(Ab + (size_t)ro * K + co, &As[ch*512]);
      gload16(Bb + (size_t)ro * K + co, &Bs[ch*512]);
    }
    __syncthreads();
    bf16x8 av[4], bv[4];
    #pragma unroll
    for (int mi = 0; mi < 4; mi++)
      av[mi] = *(const bf16x8*)&As[(wm*64 + mi*16 + (lane & 15)) * 32 + (lane >> 4) * 8];
    #pragma unroll
    for (int nj = 0; nj < 4; nj++)
      bv[nj] = *(const bf16x8*)&Bs[(wn*64 + nj*16 + (lane & 15)) * 32 + (lane >> 4) * 8];
    #pragma unroll
    for (int mi = 0; mi < 4; mi++)
      #pragma unroll
      for (int nj = 0; nj < 4; nj++)
        acc[mi][nj] = __builtin_amdgcn_mfma_f32_16x16x32_bf16(av[mi], bv[nj], acc[mi][nj], 0, 0, 0);
    __syncthreads();
  }
  if constexpr (MODE == 0){
    const int ldc = gridDim.y * 128;
    #pragma unroll
    for (int mi = 0; mi < 4; mi++)
      #pragma unroll
      for (int nj = 0; nj < 4; nj++){
        int rm0 = blockIdx.x*128 + wm*64 + mi*16 + (lane >> 4) * 4;
        int cn  = blockIdx.y*128 + wn*64 + nj*16 + (lane & 15);
        #pragma unroll
        for (int j = 0; j < 4; j++)
          g.C[(size_t)(rm0 + j) * ldc + cn] = (short)f2bf(acc[mi][nj][j] * g.scale);
      }
  } else {
    #pragma unroll
    for (int mi = 0; mi < 4; mi++)
      #pragma unroll
      for (int nj = 0; nj < 4; nj++){
        int rm0 = blockIdx.x*128 + wm*64 + mi*16 + (lane >> 4) * 4;
        int cn  = blockIdx.y*128 + wn*64 + nj*16 + (lane & 15);
        #pragma unroll
        for (int j = 0; j < 4; j++){
          float base = acc[mi][nj][j] + s_bi[cn];
          #pragma unroll
          for (int c = 0; c < 8; c++)
            p.X[((size_t)(rm0 + j) * 8 + c) * 256 + cn] = (short)f2bf(base + s_emb[c*256 + cn]);
        }
      }
  }
}

// ---------------- attention: scores/softmax/attn@x, one wave per batch ----------------
__global__ __launch_bounds__(256) void k_attn(const short* X, short* T,
    const float* cq, const float* ck, const float* c0p){
  const int tid = threadIdx.x, lane = tid & 63, w = tid >> 6;
  const int b = blockIdx.x * 4 + w;
  __shared__ alignas(16) short Ts[4][8][264];
  __shared__ alignas(16) short Xs[4][8][264];
  __shared__ float cqs[256], cks[256];
  cqs[tid] = cq[tid]; cks[tid] = ck[tid];
  const size_t base = (size_t)b * 2048;
  #pragma unroll
  for (int it = 0; it < 4; it++){
    int gi = it*512 + lane*8;
    int r = gi >> 8, c = gi & 255;
    *(uint4*)&Ts[w][r][c] = *(const uint4*)(T + base + gi);
    *(uint4*)&Xs[w][r][c] = *(const uint4*)(X + base + gi);
  }
  __syncthreads();
  const int n = lane >> 3, m = lane & 7;
  float s = 0.f;
  #pragma unroll 4
  for (int d0 = 0; d0 < 256; d0 += 8){
    uint4 ta = *(const uint4*)&Ts[w][n][d0];
    uint4 xa = *(const uint4*)&Xs[w][m][d0];
    s = dot8(ta, xa, s);
  }
  // sq_n = x_n . cq ; sk_n = x_n . ck  (octet n reduces over its row)
  float pq = 0.f, pk = 0.f;
  #pragma unroll
  for (int i = 0; i < 32; i += 8){
    uint4 xv = *(const uint4*)&Xs[w][n][m*32 + i];
    float xf[8]; unpack8(xv, xf);
    #pragma unroll
    for (int j = 0; j < 8; j++){
      pq = fmaf(xf[j], cqs[m*32 + i + j], pq);
      pk = fmaf(xf[j], cks[m*32 + i + j], pk);
    }
  }
  #pragma unroll
  for (int o = 1; o < 8; o <<= 1){ pq += __shfl_xor(pq, o); pk += __shfl_xor(pk, o); }
  float skm = __shfl(pk, m << 3);     // sk of row m (from octet m)
  s = s + pq + skm + c0p[0];
  const unsigned long long MASK64 = 0x02191D69752B857EULL;  // ADJ rows as bytes
  bool ok = (MASK64 >> (lane)) & 1ull;  // bit n*8+m == lane
  float sv = ok ? s : -3.0e38f;
  float mx = sv;
  #pragma unroll
  for (int o = 1; o < 8; o <<= 1) mx = fmaxf(mx, __shfl_xor(mx, o));
  float e = ok ? __expf(sv - mx) : 0.f;
  float sum = e;
  #pragma unroll
  for (int o = 1; o < 8; o <<= 1) sum += __shfl_xor(sum, o);
  float at = e / sum;
  float am[8];
  #pragma unroll
  for (int mm = 0; mm < 8; mm++) am[mm] = __shfl(at, (n << 3) + mm);
  // y[n] = sum_m attn[n][m] * x[m]; lane (n,m) handles d = m*8 + cb*64, in-place over T
  #pragma unroll
  for (int cb = 0; cb < 4; cb++){
    int d0 = m*8 + cb*64;
    float a8[8] = {0,0,0,0,0,0,0,0};
    #pragma unroll
    for (int mm = 0; mm < 8; mm++){
      uint4 xv = *(const uint4*)&Xs[w][mm][d0];
      float xf[8]; unpack8(xv, xf);
      #pragma unroll
      for (int j = 0; j < 8; j++) a8[j] = fmaf(am[mm], xf[j], a8[j]);
    }
    *(uint4*)(T + base + n*256 + d0) = pack8(a8);
  }
}

// ---------------- BM=64 x BN=256 GEMM with fused epilogue ----------------
// MODE 2: out = Y@Wvo + cvo; X = LN(X + out)   (writes X bf16)
// MODE 3: A = GDP-reduce(X); p = LN(A@Wp + bp); out = gelu_erf(p)  (writes f32)
template<int MODE>
__global__ __launch_bounds__(256) void k_gemmW(const short* Ax, const short* Bt,
    const float* addv, const float* gv, const float* bv2, short* Xio, float* outp){
  const int K = 256;
  const int tid = threadIdx.x, lane = tid & 63, w = tid >> 6;
  __shared__ alignas(16) short As[64*32];
  __shared__ alignas(16) short Bs[256*32];
  __shared__ alignas(16) unsigned short Ob[64*256];
  __shared__ float s_add[256], s_g[256], s_b[256];
  s_add[tid] = addv[tid]; s_g[tid] = gv[tid]; s_b[tid] = bv2[tid];
  const int r0 = blockIdx.x * 64;
  f32x4 acc[4][4] = {};
  for (int k0 = 0; k0 < K; k0 += 32){
    if constexpr (MODE == 2){
      const short* ga = Ax + (size_t)(r0 + w*16 + (lane >> 2)) * K + k0 + (lane & 3) * 8;
      gload16(ga, &As[w*512]);
    } else {
      const float GDPc[8] = {0.4f,0.15f,0.12f,0.1f,0.08f,0.08f,0.05f,0.02f};
      int row = tid >> 2, kk = (tid & 3) * 8;
      const short* xr = Ax + ((size_t)(r0 + row) * 8) * 256 + k0 + kk;
      float v8[8] = {0,0,0,0,0,0,0,0};
      #pragma unroll
      for (int c = 0; c < 8; c++){
        uint4 xv = *(const uint4*)(xr + (size_t)c * 256);
        float xf[8]; unpack8(xv, xf);
        #pragma unroll
        for (int j = 0; j < 8; j++) v8[j] = fmaf(GDPc[c], xf[j], v8[j]);
      }
      *(uint4*)&As[row*32 + kk] = pack8(v8);
    }
    #pragma unroll
    for (int i = 0; i < 4; i++){
      int ch = w*4 + i;
      const short* gb = Bt + (size_t)(ch*16 + (lane >> 2)) * K + k0 + (lane & 3) * 8;
      gload16(gb, &Bs[ch*512]);
    }
    __syncthreads();
    bf16x8 av[4], bvv[4];
    #pragma unroll
    for (int mi = 0; mi < 4; mi++)
      av[mi] = *(const bf16x8*)&As[(mi*16 + (lane & 15)) * 32 + (lane >> 4) * 8];
    #pragma unroll
    for (int nj = 0; nj < 4; nj++)
      bvv[nj] = *(const bf16x8*)&Bs[(w*64 + nj*16 + (lane & 15)) * 32 + (lane >> 4) * 8];
    #pragma unroll
    for (int mi = 0; mi < 4; mi++)
      #pragma unroll
      for (int nj = 0; nj < 4; nj++)
        acc[mi][nj] = __builtin_amdgcn_mfma_f32_16x16x32_bf16(av[mi], bvv[nj], acc[mi][nj], 0, 0, 0);
    __syncthreads();
  }
  #pragma unroll
  for (int mi = 0; mi < 4; mi++)
    #pragma unroll
    for (int nj = 0; nj < 4; nj++){
      int rr0 = mi*16 + (lane >> 4) * 4;
      int cc  = w*64 + nj*16 + (lane & 15);
      #pragma unroll
      for (int j = 0; j < 4; j++)
        Ob[(rr0 + j) * 256 + cc] = f2bf(acc[mi][nj][j] + s_add[cc]);
    }
  __syncthreads();
  // LayerNorm: 4 lanes per row (64 cols each)
  int row = tid >> 2, part = tid & 3;
  int cb0 = part * 64;
  const short* xg = Xio + (size_t)(r0 + row) * 256;   // only deref'd in MODE 2
  float sm = 0.f, s2 = 0.f;
  for (int i = 0; i < 64; i += 8){
    uint4 ov = *(const uint4*)&Ob[row*256 + cb0 + i];
    float of[8]; unpack8(ov, of);
    if constexpr (MODE == 2){
      uint4 xv = *(const uint4*)(xg + cb0 + i);
      float xf[8]; unpack8(xv, xf);
      #pragma unroll
      for (int j = 0; j < 8; j++){ float t = of[j] + xf[j]; sm += t; s2 = fmaf(t, t, s2); }
    } else {
      #pragma unroll
      for (int j = 0; j < 8; j++){ float t = of[j]; sm += t; s2 = fmaf(t, t, s2); }
    }
  }
  sm += __shfl_xor(sm, 1); sm += __shfl_xor(sm, 2);
  s2 += __shfl_xor(s2, 1); s2 += __shfl_xor(s2, 2);
  float mean = sm * (1.f/256.f);
  float var  = s2 * (1.f/256.f) - mean * mean;
  float rstd = rsqrtf(fmaxf(var, 0.f) + 1e-5f);
  for (int i = 0; i < 64; i += 8){
    int c = cb0 + i;
    uint4 ov = *(const uint4*)&Ob[row*256 + c];
    float of[8]; unpack8(ov, of);
    float y8[8];
    if constexpr (MODE == 2){
      uint4 xv = *(const uint4*)(xg + c);
      float xf[8]; unpack8(xv, xf);
      #pragma unroll
      for (int j = 0; j < 8; j++){
        float t = of[j] + xf[j];
        y8[j] = (t - mean) * rstd * s_g[c + j] + s_b[c + j];
      }
      *(uint4*)(Xio + (size_t)(r0 + row) * 256 + c) = pack8(y8);
    } else {
      #pragma unroll
      for (int j = 0; j < 8; j++){
        float t = of[j];
        float y = (t - mean) * rstd * s_g[c + j] + s_b[c + j];
        y8[j] = 0.5f * y * (1.0f + erff(y * 0.70710678118654752f));
      }
      float* op = outp + (size_t)(r0 + row) * 256 + c;
      float4 st0 = {y8[0], y8[1], y8[2], y8[3]};
      float4 st1 = {y8[4], y8[5], y8[6], y8[7]};
      *(float4*)op = st0; *(float4*)(op + 4) = st1;
    }
  }
}

extern "C" void kernel_launch(void* const* d_in, const int* in_sizes, int n_in,
                              void* d_out, int out_size, void* d_ws, size_t ws_size,
                              hipStream_t stream){
  (void)in_sizes; (void)n_in; (void)out_size; (void)ws_size;
  const float* rf  = (const float*)d_in[0];
  const float* Wi  = (const float*)d_in[1];
  const float* bi  = (const float*)d_in[2];
  const float* emb = (const float*)d_in[3];
  const float* Wq  = (const float*)d_in[4];
  const float* bq  = (const float*)d_in[5];
  const float* Wk  = (const float*)d_in[6];
  const float* bk  = (const float*)d_in[7];
  const float* Wv  = (const float*)d_in[8];
  const float* bv  = (const float*)d_in[9];
  const float* Wo  = (const float*)d_in[10];
  const float* bo  = (const float*)d_in[11];
  const float* lng = (const float*)d_in[12];
  const float* lnb = (const float*)d_in[13];
  const float* Wp  = (const float*)d_in[14];
  const float* bp  = (const float*)d_in[15];
  const float* lpg = (const float*)d_in[16];
  const float* lpb = (const float*)d_in[17];
  (void)Wq; (void)Wv;

  // Workspace layout (peak ~65.1 MB):
  //   X [65536][256] bf16 @ 0        (transient weight copies staged here pre-X)
  //   T [65536][256] bf16 @ 32MB     (rfb staged here pre-T)
  //   small persistent tail @ 64MB
  char* ws = (char*)d_ws;
  short* X    = (short*)(ws);
  short* T    = (short*)(ws + 33554432ull);
  // transient: consumed by precompute GEMMs / input-proj GEMM before X/T written
  short* Wqb  = (short*)(ws);                      // [3][256][1024] bf16 (in X region)
  short* Wkb  = (short*)(ws + 1572864ull);
  short* Wvb  = (short*)(ws + 3145728ull);
  short* WoTb = (short*)(ws + 4718592ull);         // [3][256][1024] (Wo^T per layer)
  short* rfb  = (short*)(ws + 33554432ull);        // [8192][512] bf16 (in T region)
  // persistent tail
  short* WiTb = (short*)(ws + 67108864ull);        // [256][512]
  short* WpTb = (short*)(ws + 67371008ull);        // [256][256]
  short* Wqk  = (short*)(ws + 67502080ull);        // [3][256][256] Bt for GEMM1 (scaled 1/16)
  short* Wvo  = (short*)(ws + 67895296ull);        // [3][256][256] Bt for GEMM2
  float* cqv  = (float*)(ws + 68288512ull);
  float* ckv  = (float*)(ws + 68291584ull);
  float* cvov = (float*)(ws + 68294656ull);
  float* c0v  = (float*)(ws + 68297728ull);

  { CvP cv;
    cv.src[0]=rf; cv.dst[0]=rfb;
    cv.src[1]=Wq; cv.dst[1]=Wqb;
    cv.src[2]=Wk; cv.dst[2]=Wkb;
    cv.src[3]=Wv; cv.dst[3]=Wvb;
    // rf: 8192*512/2048 = 2048 blocks; Wq/Wk/Wv: 3*256*1024/2048 = 384 blocks each
    cv.boff[0]=0; cv.boff[1]=2048; cv.boff[2]=2432; cv.boff[3]=2816; cv.boff[4]=3200;
    k_convert<<<dim3(3200), dim3(256), 0, stream>>>(cv); }

  { TrP tp;
    tp.src[0]=Wi;          tp.dst[0]=WiTb;          tp.rows[0]=512;  tp.cols[0]=256;
    tp.src[1]=Wo;          tp.dst[1]=WoTb;          tp.rows[1]=1024; tp.cols[1]=256;
    tp.src[2]=Wo+262144;   tp.dst[2]=WoTb+262144;   tp.rows[2]=1024; tp.cols[2]=256;
    tp.src[3]=Wo+524288;   tp.dst[3]=WoTb+524288;   tp.rows[3]=1024; tp.cols[3]=256;
    tp.src[4]=Wp;          tp.dst[4]=WpTb;          tp.rows[4]=256;  tp.cols[4]=256;
    tp.toff[0]=0; tp.toff[1]=32; tp.toff[2]=96; tp.toff[3]=160; tp.toff[4]=224; tp.toff[5]=240;
    k_transpose<<<dim3(240), dim3(256), 0, stream>>>(tp); }

  // bias-fold vectors from the staged bf16 rows (12 blocks, ~5us)
  k_vecs2<<<dim3(4, 3), dim3(256), 0, stream>>>(Wqb, Wkb, WoTb, bq, bk, bv, bo,
                                                cqv, ckv, cvov, c0v);

  { GemmP g{};   // Wqk_bt[j][i] = (1/16) sum_d Wk[j,d]Wq[i,d] ; Wvo_bt[n][k] = sum_d Wo[d,n]Wv[k,d]
    for (int l = 0; l < 3; l++){
      g.d[l]   = GDesc{ Wkb  + l*262144, Wqb + l*262144, Wqk + l*65536, 1024, 0.0625f };
      g.d[3+l] = GDesc{ WoTb + l*262144, Wvb + l*262144, Wvo + l*65536, 1024, 1.0f };
    }
    k_gemm128<0><<<dim3(2,2,6), dim3(256), 0, stream>>>(g); }

  { GemmP g{};   // X[b,c,:] = rf@Wi + bi + emb[c]   (consumes rfb + weight copies, writes X)
    g.d[0] = GDesc{ rfb, WiTb, T, 512, 1.0f };
    g.bi = bi; g.emb = emb; g.X = X;
    k_gemm128<1><<<dim3(64,2,1), dim3(256), 0, stream>>>(g); }

  for (int l = 0; l < 3; l++){
    { GemmP g{};   // T = X @ Wqk (pre-scaled)
      g.d[0] = GDesc{ X, Wqk + l*65536, T, 256, 1.0f };
      k_gemm128<0><<<dim3(512,2,1), dim3(256), 0, stream>>>(g); }
    k_attn<<<dim3(2048), dim3(256), 0, stream>>>(X, T, cqv + l*256, ckv + l*256, c0v + l);
    k_gemmW<2><<<dim3(1024), dim3(256), 0, stream>>>(T, Wvo + l*65536, cvov + l*256,
                                                     lng + l*256, lnb + l*256, X, nullptr);
  }
  k_gemmW<3><<<dim3(128), dim3(256), 0, stream>>>(X, WpTb, bp, lpg, lpb, X, (float*)d_out);
}